// Round 1
// baseline (2438.689 us; speedup 1.0000x reference)
//
#include <hip/hip_runtime.h>

#define N_NODES 50000
#define E_EDGES 800000
#define E_TOT   (E_EDGES + N_NODES)   // edges + self loops
#define P_PAIRS 200000
#define IN_DIM  32
#define HID     64
#define HEADS   4
#define D       256
#define NEG_SLOPE 0.2f

// ---- monotone float<->uint encoding so atomicMax(uint) == float max ----
__device__ __forceinline__ unsigned enc_f(float f) {
  unsigned u = __float_as_uint(f);
  return (u & 0x80000000u) ? ~u : (u | 0x80000000u);
}
__device__ __forceinline__ float dec_f(unsigned u) {
  return __uint_as_float((u & 0x80000000u) ? (u & 0x7FFFFFFFu) : ~u);
}
#define ENC_NEG_INF 0x007FFFFFu   // enc(-inf)

__device__ __forceinline__ void edge_sd(const int* __restrict__ ei, int e, int& s, int& d) {
  if (e < E_EDGES) { s = ei[e]; d = ei[E_EDGES + e]; }
  else             { s = d = e - E_EDGES; }
}

// ---- GEMM1: [N,32] @ [32,256] ----
__global__ __launch_bounds__(256) void gemm_l1(const float* __restrict__ x,
                                               const float* __restrict__ W,
                                               float* __restrict__ out) {
  __shared__ float Ws[IN_DIM * D];      // 32KB
  __shared__ float xs[32][IN_DIM + 1];
  for (int i = threadIdx.x; i < IN_DIM * D; i += 256) Ws[i] = W[i];
  int row0 = blockIdx.x * 32;
  for (int i = threadIdx.x; i < 32 * IN_DIM; i += 256) {
    int r = i >> 5, k = i & 31;
    int rr = row0 + r;
    xs[r][k] = (rr < N_NODES) ? x[rr * IN_DIM + k] : 0.f;
  }
  __syncthreads();
  int c = threadIdx.x;
  #pragma unroll 4
  for (int r = 0; r < 32; ++r) {
    float acc = 0.f;
    #pragma unroll
    for (int k = 0; k < IN_DIM; ++k) acc += xs[r][k] * Ws[k * D + c];
    int rr = row0 + r;
    if (rr < N_NODES) out[(size_t)rr * D + c] = acc;
  }
}

// ---- GEMM2: [N,256] @ [256,256] ----
__global__ __launch_bounds__(256) void gemm_l2(const float* __restrict__ A,
                                               const float* __restrict__ W,
                                               float* __restrict__ out) {
  __shared__ float As[32][33];
  __shared__ float Bs[32][D];           // 32KB
  int row0 = blockIdx.x * 32;
  int c = threadIdx.x;
  float acc[32];
  #pragma unroll
  for (int r = 0; r < 32; ++r) acc[r] = 0.f;
  for (int kc = 0; kc < D; kc += 32) {
    __syncthreads();
    for (int i = threadIdx.x; i < 32 * 32; i += 256) {
      int r = i >> 5, k = i & 31;
      int rr = row0 + r;
      As[r][k] = (rr < N_NODES) ? A[(size_t)rr * D + kc + k] : 0.f;
    }
    for (int i = threadIdx.x; i < 32 * D; i += 256) {
      int k = i >> 8, cc = i & 255;
      Bs[k][cc] = W[(size_t)(kc + k) * D + cc];
    }
    __syncthreads();
    #pragma unroll
    for (int k = 0; k < 32; ++k) {
      float b = Bs[k][c];
      #pragma unroll
      for (int r = 0; r < 32; ++r) acc[r] += As[r][k] * b;
    }
  }
  #pragma unroll
  for (int r = 0; r < 32; ++r) {
    int rr = row0 + r;
    if (rr < N_NODES) out[(size_t)rr * D + c] = acc[r];
  }
}

// ---- per-(node,head) attention logits: one wave per (n,h) ----
__global__ __launch_bounds__(256) void alphas_k(const float* __restrict__ h,
                                                const float* __restrict__ asrc,
                                                const float* __restrict__ adst,
                                                float* __restrict__ alps,
                                                float* __restrict__ alpd) {
  int wid = (blockIdx.x * 256 + threadIdx.x) >> 6;
  int lane = threadIdx.x & 63;
  if (wid >= N_NODES * HEADS) return;
  int n = wid >> 2, hh = wid & 3;
  float v = h[(size_t)n * D + hh * HID + lane];
  float s = v * asrc[hh * HID + lane];
  float d = v * adst[hh * HID + lane];
  #pragma unroll
  for (int off = 32; off; off >>= 1) {
    s += __shfl_down(s, off);
    d += __shfl_down(d, off);
  }
  if (lane == 0) { alps[wid] = s; alpd[wid] = d; }
}

__global__ void init_md(unsigned* __restrict__ mmax, float* __restrict__ denom) {
  int g = blockIdx.x * blockDim.x + threadIdx.x;
  if (g < N_NODES * HEADS) { mmax[g] = ENC_NEG_INF; denom[g] = 0.f; }
}

// ---- edge pass 1: segment max (transformed-uint atomicMax) ----
__global__ void edge_max_k(const int* __restrict__ ei,
                           const float* __restrict__ alps,
                           const float* __restrict__ alpd,
                           unsigned* __restrict__ mmax) {
  int g = blockIdx.x * blockDim.x + threadIdx.x;
  if (g >= E_TOT * HEADS) return;
  int e = g >> 2, hh = g & 3;
  int s, d; edge_sd(ei, e, s, d);
  float raw = alps[s * HEADS + hh] + alpd[d * HEADS + hh];
  float v = raw > 0.f ? raw : NEG_SLOPE * raw;
  atomicMax(&mmax[d * HEADS + hh], enc_f(v));
}

// ---- edge pass 2: denom = segment sum of exp(e - m) ----
__global__ void edge_denom_k(const int* __restrict__ ei,
                             const float* __restrict__ alps,
                             const float* __restrict__ alpd,
                             const unsigned* __restrict__ mmax,
                             float* __restrict__ denom) {
  int g = blockIdx.x * blockDim.x + threadIdx.x;
  if (g >= E_TOT * HEADS) return;
  int e = g >> 2, hh = g & 3;
  int s, d; edge_sd(ei, e, s, d);
  float raw = alps[s * HEADS + hh] + alpd[d * HEADS + hh];
  float v = raw > 0.f ? raw : NEG_SLOPE * raw;
  float ex = expf(v - dec_f(mmax[d * HEADS + hh]));
  atomicAdd(&denom[d * HEADS + hh], ex);
}

// ---- edge pass 3: aggregate sum(ex * h[src]) into agg[dst] (one block/edge) ----
__global__ __launch_bounds__(256) void edge_agg_k(const int* __restrict__ ei,
                                                  const float* __restrict__ alps,
                                                  const float* __restrict__ alpd,
                                                  const unsigned* __restrict__ mmax,
                                                  const float* __restrict__ h,
                                                  float* __restrict__ agg) {
  int e = blockIdx.x;
  int c = threadIdx.x;
  int hh = c >> 6;
  int s, d; edge_sd(ei, e, s, d);
  float raw = alps[s * HEADS + hh] + alpd[d * HEADS + hh];
  float v = raw > 0.f ? raw : NEG_SLOPE * raw;
  float ex = expf(v - dec_f(mmax[d * HEADS + hh]));
  atomicAdd(&agg[(size_t)d * D + c], h[(size_t)s * D + c] * ex);
}

// ---- epilogue: out = relu(agg/denom + b), in place ----
__global__ void finish_k(float* __restrict__ agg,
                         const float* __restrict__ denom,
                         const float* __restrict__ b) {
  int g = blockIdx.x * blockDim.x + threadIdx.x;
  if (g >= N_NODES * D) return;
  int n = g >> 8, c = g & 255, hh = c >> 6;
  float v = agg[g] / (denom[n * HEADS + hh] + 1e-16f) + b[c];
  agg[g] = v > 0.f ? v : 0.f;
}

// ---- pair scoring: one wave per pair ----
__global__ __launch_bounds__(256) void pair_k(const float* __restrict__ h,
                                              const int* __restrict__ pairs,
                                              const float* __restrict__ hw,
                                              const float* __restrict__ hb,
                                              float* __restrict__ out) {
  int wid = (blockIdx.x * 256 + threadIdx.x) >> 6;
  int lane = threadIdx.x & 63;
  if (wid >= P_PAIRS) return;
  int a = pairs[wid * 2], b = pairs[wid * 2 + 1];
  int half = lane >> 5;
  int l = lane & 31;
  const float* hp = h + (size_t)(half ? b : a) * D + l * 8;
  const float* wp = hw + half * D + l * 8;
  float4 v0 = *(const float4*)hp, v1 = *(const float4*)(hp + 4);
  float4 w0 = *(const float4*)wp, w1 = *(const float4*)(wp + 4);
  float s = v0.x * w0.x + v0.y * w0.y + v0.z * w0.z + v0.w * w0.w
          + v1.x * w1.x + v1.y * w1.y + v1.z * w1.z + v1.w * w1.w;
  #pragma unroll
  for (int off = 32; off; off >>= 1) s += __shfl_down(s, off);
  if (lane == 0) out[wid] = s + hb[0];
}

extern "C" void kernel_launch(void* const* d_in, const int* in_sizes, int n_in,
                              void* d_out, int out_size, void* d_ws, size_t ws_size,
                              hipStream_t stream) {
  const float* x    = (const float*)d_in[0];
  const int*   ei   = (const int*)d_in[1];
  const int*   prs  = (const int*)d_in[2];
  const float* W1   = (const float*)d_in[3];
  const float* as1  = (const float*)d_in[4];
  const float* ad1  = (const float*)d_in[5];
  const float* b1   = (const float*)d_in[6];
  const float* W2   = (const float*)d_in[7];
  const float* as2  = (const float*)d_in[8];
  const float* ad2  = (const float*)d_in[9];
  const float* b2   = (const float*)d_in[10];
  const float* hw   = (const float*)d_in[11];
  const float* hb   = (const float*)d_in[12];
  float* out = (float*)d_out;

  char* w = (char*)d_ws;
  float* buf0 = (float*)w;            w += (size_t)N_NODES * D * 4;   // h (GEMM out)
  float* buf1 = (float*)w;            w += (size_t)N_NODES * D * 4;   // agg / layer out
  float* alps = (float*)w;            w += (size_t)N_NODES * HEADS * 4;
  float* alpd = (float*)w;            w += (size_t)N_NODES * HEADS * 4;
  unsigned* mmax = (unsigned*)w;      w += (size_t)N_NODES * HEADS * 4;
  float* denom = (float*)w;           w += (size_t)N_NODES * HEADS * 4;

  const int nBlk32 = (N_NODES + 31) / 32;                 // 1563
  const int nhBlk  = (N_NODES * HEADS + 255) / 256;       // 782
  const int waveBlkNH = (N_NODES * HEADS) / 4;            // 50000 (waves of 64, 4/block)
  const int ehBlk  = (E_TOT * HEADS + 255) / 256;         // 13282
  const int ndBlk  = (N_NODES * D + 255) / 256;           // 50000
  const int pairBlk = (P_PAIRS + 3) / 4;                  // 50000

  // ---------- layer 1 ----------
  gemm_l1<<<nBlk32, 256, 0, stream>>>(x, W1, buf0);
  alphas_k<<<waveBlkNH, 256, 0, stream>>>(buf0, as1, ad1, alps, alpd);
  init_md<<<nhBlk, 256, 0, stream>>>(mmax, denom);
  hipMemsetAsync(buf1, 0, (size_t)N_NODES * D * 4, stream);
  edge_max_k<<<ehBlk, 256, 0, stream>>>(ei, alps, alpd, mmax);
  edge_denom_k<<<ehBlk, 256, 0, stream>>>(ei, alps, alpd, mmax, denom);
  edge_agg_k<<<E_TOT, 256, 0, stream>>>(ei, alps, alpd, mmax, buf0, buf1);
  finish_k<<<ndBlk, 256, 0, stream>>>(buf1, denom, b1);

  // ---------- layer 2 ----------
  gemm_l2<<<nBlk32, 256, 0, stream>>>(buf1, W2, buf0);
  alphas_k<<<waveBlkNH, 256, 0, stream>>>(buf0, as2, ad2, alps, alpd);
  init_md<<<nhBlk, 256, 0, stream>>>(mmax, denom);
  hipMemsetAsync(buf1, 0, (size_t)N_NODES * D * 4, stream);
  edge_max_k<<<ehBlk, 256, 0, stream>>>(ei, alps, alpd, mmax);
  edge_denom_k<<<ehBlk, 256, 0, stream>>>(ei, alps, alpd, mmax, denom);
  edge_agg_k<<<E_TOT, 256, 0, stream>>>(ei, alps, alpd, mmax, buf0, buf1);
  finish_k<<<ndBlk, 256, 0, stream>>>(buf1, denom, b2);

  // ---------- pair head ----------
  pair_k<<<pairBlk, 256, 0, stream>>>(buf1, prs, hw, hb, out);
}

// Round 2
// 1239.735 us; speedup vs baseline: 1.9671x; 1.9671x over previous
//
#include <hip/hip_runtime.h>

#define N_NODES 50000
#define E_EDGES 800000
#define E_TOT   (E_EDGES + N_NODES)   // edges + self loops
#define P_PAIRS 200000
#define IN_DIM  32
#define HID     64
#define HEADS   4
#define D       256
#define NEG_SLOPE 0.2f
#define SCAN_BS 1024

__device__ __forceinline__ void edge_sd(const int* __restrict__ ei, int e, int& s, int& d) {
  if (e < E_EDGES) { s = ei[e]; d = ei[E_EDGES + e]; }
  else             { s = d = e - E_EDGES; }
}

// ---- GEMM1: [N,32] @ [32,256] ----
__global__ __launch_bounds__(256) void gemm_l1(const float* __restrict__ x,
                                               const float* __restrict__ W,
                                               float* __restrict__ out) {
  __shared__ float Ws[IN_DIM * D];      // 32KB
  __shared__ float xs[32][IN_DIM + 1];
  for (int i = threadIdx.x; i < IN_DIM * D; i += 256) Ws[i] = W[i];
  int row0 = blockIdx.x * 32;
  for (int i = threadIdx.x; i < 32 * IN_DIM; i += 256) {
    int r = i >> 5, k = i & 31;
    int rr = row0 + r;
    xs[r][k] = (rr < N_NODES) ? x[rr * IN_DIM + k] : 0.f;
  }
  __syncthreads();
  int c = threadIdx.x;
  #pragma unroll 4
  for (int r = 0; r < 32; ++r) {
    float acc = 0.f;
    #pragma unroll
    for (int k = 0; k < IN_DIM; ++k) acc += xs[r][k] * Ws[k * D + c];
    int rr = row0 + r;
    if (rr < N_NODES) out[(size_t)rr * D + c] = acc;
  }
}

// ---- GEMM2: [N,256] @ [256,256] ----
__global__ __launch_bounds__(256) void gemm_l2(const float* __restrict__ A,
                                               const float* __restrict__ W,
                                               float* __restrict__ out) {
  __shared__ float As[32][33];
  __shared__ float Bs[32][D];           // 32KB
  int row0 = blockIdx.x * 32;
  int c = threadIdx.x;
  float acc[32];
  #pragma unroll
  for (int r = 0; r < 32; ++r) acc[r] = 0.f;
  for (int kc = 0; kc < D; kc += 32) {
    __syncthreads();
    for (int i = threadIdx.x; i < 32 * 32; i += 256) {
      int r = i >> 5, k = i & 31;
      int rr = row0 + r;
      As[r][k] = (rr < N_NODES) ? A[(size_t)rr * D + kc + k] : 0.f;
    }
    for (int i = threadIdx.x; i < 32 * D; i += 256) {
      int k = i >> 8, cc = i & 255;
      Bs[k][cc] = W[(size_t)(kc + k) * D + cc];
    }
    __syncthreads();
    #pragma unroll
    for (int k = 0; k < 32; ++k) {
      float b = Bs[k][c];
      #pragma unroll
      for (int r = 0; r < 32; ++r) acc[r] += As[r][k] * b;
    }
  }
  #pragma unroll
  for (int r = 0; r < 32; ++r) {
    int rr = row0 + r;
    if (rr < N_NODES) out[(size_t)rr * D + c] = acc[r];
  }
}

// ---- per-(node,head) attention logits: one wave per (n,h) ----
__global__ __launch_bounds__(256) void alphas_k(const float* __restrict__ h,
                                                const float* __restrict__ asrc,
                                                const float* __restrict__ adst,
                                                float* __restrict__ alps,
                                                float* __restrict__ alpd) {
  int wid = (blockIdx.x * 256 + threadIdx.x) >> 6;
  int lane = threadIdx.x & 63;
  if (wid >= N_NODES * HEADS) return;
  int n = wid >> 2, hh = wid & 3;
  float v = h[(size_t)n * D + hh * HID + lane];
  float s = v * asrc[hh * HID + lane];
  float d = v * adst[hh * HID + lane];
  #pragma unroll
  for (int off = 32; off; off >>= 1) {
    s += __shfl_down(s, off);
    d += __shfl_down(d, off);
  }
  if (lane == 0) { alps[wid] = s; alpd[wid] = d; }
}

// ================= CSR build (dst-grouped) =================
__global__ void count_k(const int* __restrict__ ei, int* __restrict__ deg) {
  int e = blockIdx.x * 256 + threadIdx.x;
  if (e >= E_TOT) return;
  int s, d; edge_sd(ei, e, s, d);
  atomicAdd(&deg[d], 1);
}

__global__ __launch_bounds__(SCAN_BS) void scan_block_k(const int* __restrict__ in,
                                                        int* __restrict__ out,
                                                        int* __restrict__ bsum, int n) {
  __shared__ int tmp[SCAN_BS];
  int g = blockIdx.x * SCAN_BS + threadIdx.x;
  tmp[threadIdx.x] = (g < n) ? in[g] : 0;
  __syncthreads();
  for (int off = 1; off < SCAN_BS; off <<= 1) {
    int t = 0;
    if ((int)threadIdx.x >= off) t = tmp[threadIdx.x - off];
    __syncthreads();
    if ((int)threadIdx.x >= off) tmp[threadIdx.x] += t;
    __syncthreads();
  }
  if (g < n) out[g] = tmp[threadIdx.x];
  if (threadIdx.x == SCAN_BS - 1) bsum[blockIdx.x] = tmp[SCAN_BS - 1];
}

__global__ void scan_top_k(int* __restrict__ bsum, int nb) {
  __shared__ int tmp[256];
  tmp[threadIdx.x] = ((int)threadIdx.x < nb) ? bsum[threadIdx.x] : 0;
  __syncthreads();
  for (int off = 1; off < 256; off <<= 1) {
    int t = 0;
    if ((int)threadIdx.x >= off) t = tmp[threadIdx.x - off];
    __syncthreads();
    if ((int)threadIdx.x >= off) tmp[threadIdx.x] += t;
    __syncthreads();
  }
  if ((int)threadIdx.x < nb) bsum[threadIdx.x] = tmp[threadIdx.x];
}

__global__ void add_off_k(const int* __restrict__ scan_out,
                          const int* __restrict__ bsum,
                          int* __restrict__ rowptr) {
  int g = blockIdx.x * 256 + threadIdx.x;
  if (g >= N_NODES) return;
  int blk = g / SCAN_BS;
  int add = blk ? bsum[blk - 1] : 0;
  rowptr[g + 1] = scan_out[g] + add;
  if (g == 0) rowptr[0] = 0;
}

__global__ void scatter_k(const int* __restrict__ ei,
                          const int* __restrict__ rowptr,
                          int* __restrict__ pos, int* __restrict__ csr) {
  int e = blockIdx.x * 256 + threadIdx.x;
  if (e >= E_TOT) return;
  int s, d; edge_sd(ei, e, s, d);
  int idx = rowptr[d] + atomicAdd(&pos[d], 1);
  csr[idx] = s;
}

// ====== fused segment-softmax + aggregation: one wave per node ======
// lane l owns channels 4l..4l+3 (head q = l>>4); h[src] read as coalesced float4
__global__ __launch_bounds__(256) void gat_gather_k(
    const int* __restrict__ rowptr, const int* __restrict__ csr,
    const float* __restrict__ alps, const float* __restrict__ alpd,
    const float* __restrict__ h, const float* __restrict__ b,
    float* __restrict__ out) {
  int wid = (blockIdx.x * 256 + threadIdx.x) >> 6;
  int lane = threadIdx.x & 63;
  if (wid >= N_NODES) return;
  int q = lane >> 4;                      // head of my 4 channels
  int beg = rowptr[wid], end = rowptr[wid + 1];
  float ad = alpd[wid * HEADS + q];

  // pass 1: per-head running max (each lane tracks its own head's max)
  float m = -1e30f;
  for (int i = beg; i < end; ++i) {
    int s = csr[i];
    float x = alps[s * HEADS + q] + ad;
    float v = fmaxf(x, NEG_SLOPE * x);    // leaky_relu, slope<1
    m = fmaxf(m, v);
  }

  // pass 2: exp-weighted accumulate
  float den = 0.f;
  float4 acc = make_float4(0.f, 0.f, 0.f, 0.f);
  for (int i = beg; i < end; ++i) {
    int s = csr[i];
    float x = alps[s * HEADS + q] + ad;
    float v = fmaxf(x, NEG_SLOPE * x);
    float ef = __expf(v - m);
    den += ef;
    float4 hv = *(const float4*)(h + (size_t)s * D + lane * 4);
    acc.x += hv.x * ef; acc.y += hv.y * ef;
    acc.z += hv.z * ef; acc.w += hv.w * ef;
  }

  float inv = 1.f / (den + 1e-16f);
  float4 bv = *(const float4*)(b + lane * 4);
  float4 o;
  o.x = fmaxf(acc.x * inv + bv.x, 0.f);
  o.y = fmaxf(acc.y * inv + bv.y, 0.f);
  o.z = fmaxf(acc.z * inv + bv.z, 0.f);
  o.w = fmaxf(acc.w * inv + bv.w, 0.f);
  *(float4*)(out + (size_t)wid * D + lane * 4) = o;
}

// ---- pair scoring: one wave per pair ----
__global__ __launch_bounds__(256) void pair_k(const float* __restrict__ h,
                                              const int* __restrict__ pairs,
                                              const float* __restrict__ hw,
                                              const float* __restrict__ hb,
                                              float* __restrict__ out) {
  int wid = (blockIdx.x * 256 + threadIdx.x) >> 6;
  int lane = threadIdx.x & 63;
  if (wid >= P_PAIRS) return;
  int a = pairs[wid * 2], b = pairs[wid * 2 + 1];
  int half = lane >> 5;
  int l = lane & 31;
  const float* hp = h + (size_t)(half ? b : a) * D + l * 8;
  const float* wp = hw + half * D + l * 8;
  float4 v0 = *(const float4*)hp, v1 = *(const float4*)(hp + 4);
  float4 w0 = *(const float4*)wp, w1 = *(const float4*)(wp + 4);
  float s = v0.x * w0.x + v0.y * w0.y + v0.z * w0.z + v0.w * w0.w
          + v1.x * w1.x + v1.y * w1.y + v1.z * w1.z + v1.w * w1.w;
  #pragma unroll
  for (int off = 32; off; off >>= 1) s += __shfl_down(s, off);
  if (lane == 0) out[wid] = s + hb[0];
}

extern "C" void kernel_launch(void* const* d_in, const int* in_sizes, int n_in,
                              void* d_out, int out_size, void* d_ws, size_t ws_size,
                              hipStream_t stream) {
  const float* x    = (const float*)d_in[0];
  const int*   ei   = (const int*)d_in[1];
  const int*   prs  = (const int*)d_in[2];
  const float* W1   = (const float*)d_in[3];
  const float* as1  = (const float*)d_in[4];
  const float* ad1  = (const float*)d_in[5];
  const float* b1   = (const float*)d_in[6];
  const float* W2   = (const float*)d_in[7];
  const float* as2  = (const float*)d_in[8];
  const float* ad2  = (const float*)d_in[9];
  const float* b2   = (const float*)d_in[10];
  const float* hw   = (const float*)d_in[11];
  const float* hb   = (const float*)d_in[12];
  float* out = (float*)d_out;

  char* w = (char*)d_ws;
  float* buf0 = (float*)w;            w += (size_t)N_NODES * D * 4;   // h (GEMM out)
  float* buf1 = (float*)w;            w += (size_t)N_NODES * D * 4;   // layer out
  float* alps = (float*)w;            w += (size_t)N_NODES * HEADS * 4;
  float* alpd = (float*)w;            w += (size_t)N_NODES * HEADS * 4;
  int* rowptr = (int*)w;              w += (size_t)(N_NODES + 1) * 4;
  int* csr    = (int*)w;              w += (size_t)E_TOT * 4;

  // CSR-build temporaries aliased into buf1 (buf1 first written by gat_gather_k,
  // which runs strictly after scatter_k on this stream)
  int* deg      = (int*)buf1;
  int* scan_out = deg + N_NODES;
  int* bsum     = scan_out + N_NODES;   // up to 64 ints

  const int nBlk32   = (N_NODES + 31) / 32;              // 1563
  const int waveBlkNH = (N_NODES * HEADS) / 4;           // 50000
  const int eBlk     = (E_TOT + 255) / 256;              // 3321
  const int nScanBlk = (N_NODES + SCAN_BS - 1) / SCAN_BS; // 49
  const int nBlk256  = (N_NODES + 255) / 256;            // 196
  const int gatherBlk = (N_NODES * 64 + 255) / 256;      // 12500
  const int pairBlk  = (P_PAIRS + 3) / 4;                // 50000

  // ---------- CSR build (once, reused by both layers) ----------
  hipMemsetAsync(deg, 0, (size_t)N_NODES * 4, stream);
  count_k<<<eBlk, 256, 0, stream>>>(ei, deg);
  scan_block_k<<<nScanBlk, SCAN_BS, 0, stream>>>(deg, scan_out, bsum, N_NODES);
  scan_top_k<<<1, 256, 0, stream>>>(bsum, nScanBlk);
  add_off_k<<<nBlk256, 256, 0, stream>>>(scan_out, bsum, rowptr);
  hipMemsetAsync(deg, 0, (size_t)N_NODES * 4, stream);   // reuse as pos
  scatter_k<<<eBlk, 256, 0, stream>>>(ei, rowptr, deg, csr);

  // ---------- layer 1 ----------
  gemm_l1<<<nBlk32, 256, 0, stream>>>(x, W1, buf0);
  alphas_k<<<waveBlkNH, 256, 0, stream>>>(buf0, as1, ad1, alps, alpd);
  gat_gather_k<<<gatherBlk, 256, 0, stream>>>(rowptr, csr, alps, alpd, buf0, b1, buf1);

  // ---------- layer 2 ----------
  gemm_l2<<<nBlk32, 256, 0, stream>>>(buf1, W2, buf0);
  alphas_k<<<waveBlkNH, 256, 0, stream>>>(buf0, as2, ad2, alps, alpd);
  gat_gather_k<<<gatherBlk, 256, 0, stream>>>(rowptr, csr, alps, alpd, buf0, b2, buf1);

  // ---------- pair head ----------
  pair_k<<<pairBlk, 256, 0, stream>>>(buf1, prs, hw, hb, out);
}

// Round 3
// 700.239 us; speedup vs baseline: 3.4827x; 1.7704x over previous
//
#include <hip/hip_runtime.h>

#define N_NODES 50000
#define E_EDGES 800000
#define E_TOT   (E_EDGES + N_NODES)   // edges + self loops
#define P_PAIRS 200000
#define IN_DIM  32
#define HID     64
#define HEADS   4
#define D       256
#define NEG_SLOPE 0.2f
#define SCAN_BS 1024

__device__ __forceinline__ void edge_sd(const int* __restrict__ ei, int e, int& s, int& d) {
  if (e < E_EDGES) { s = ei[e]; d = ei[E_EDGES + e]; }
  else             { s = d = e - E_EDGES; }
}

// ================= register-blocked fp32 GEMM: [N,KD] @ [KD,256] =================
// 64x64 tile per block, 256 threads, 4x4 micro-tile per thread.
// As stored transposed [k][row] with row-stride 68 (272B: 16B-aligned float4 reads,
// and the 4 scalar transpose-writes per float4 land in distinct banks).
template<int KD>
__global__ __launch_bounds__(256) void gemm_tile(const float* __restrict__ A,
                                                 const float* __restrict__ W,
                                                 float* __restrict__ out) {
  __shared__ float As[32][68];
  __shared__ float Bs[32][64];
  const int row0 = blockIdx.x * 64;
  const int col0 = blockIdx.y * 64;
  const int t  = threadIdx.x;
  const int tx = t & 15, ty = t >> 4;
  float acc[4][4] = {{0.f}};

  for (int kc = 0; kc < KD; kc += 32) {
    // stage A: 64 rows x 32 k (512 float4 loads, 2/thread), transpose into As
    #pragma unroll
    for (int i = 0; i < 2; ++i) {
      int idx = t + i * 256;           // 0..511
      int r = idx >> 3, k4 = idx & 7;
      int rr = row0 + r;
      float4 a = make_float4(0.f, 0.f, 0.f, 0.f);
      if (rr < N_NODES) a = *(const float4*)(A + (size_t)rr * KD + kc + k4 * 4);
      As[k4 * 4 + 0][r] = a.x;
      As[k4 * 4 + 1][r] = a.y;
      As[k4 * 4 + 2][r] = a.z;
      As[k4 * 4 + 3][r] = a.w;
    }
    // stage B: 32 k x 64 cols (512 float4 loads, 2/thread)
    #pragma unroll
    for (int i = 0; i < 2; ++i) {
      int idx = t + i * 256;
      int k = idx >> 4, c4 = idx & 15;
      *(float4*)&Bs[k][c4 * 4] =
          *(const float4*)(W + (size_t)(kc + k) * D + col0 + c4 * 4);
    }
    __syncthreads();
    #pragma unroll
    for (int k = 0; k < 32; ++k) {
      float4 av = *(const float4*)&As[k][ty * 4];
      float4 bv = *(const float4*)&Bs[k][tx * 4];
      acc[0][0] += av.x * bv.x; acc[0][1] += av.x * bv.y;
      acc[0][2] += av.x * bv.z; acc[0][3] += av.x * bv.w;
      acc[1][0] += av.y * bv.x; acc[1][1] += av.y * bv.y;
      acc[1][2] += av.y * bv.z; acc[1][3] += av.y * bv.w;
      acc[2][0] += av.z * bv.x; acc[2][1] += av.z * bv.y;
      acc[2][2] += av.z * bv.z; acc[2][3] += av.z * bv.w;
      acc[3][0] += av.w * bv.x; acc[3][1] += av.w * bv.y;
      acc[3][2] += av.w * bv.z; acc[3][3] += av.w * bv.w;
    }
    __syncthreads();
  }

  #pragma unroll
  for (int i = 0; i < 4; ++i) {
    int rr = row0 + ty * 4 + i;
    if (rr < N_NODES) {
      *(float4*)(out + (size_t)rr * D + col0 + tx * 4) =
          make_float4(acc[i][0], acc[i][1], acc[i][2], acc[i][3]);
    }
  }
}

// ---- per-(node,head) attention logits: one wave per (n,h) ----
__global__ __launch_bounds__(256) void alphas_k(const float* __restrict__ h,
                                                const float* __restrict__ asrc,
                                                const float* __restrict__ adst,
                                                float* __restrict__ alps,
                                                float* __restrict__ alpd) {
  int wid = (blockIdx.x * 256 + threadIdx.x) >> 6;
  int lane = threadIdx.x & 63;
  if (wid >= N_NODES * HEADS) return;
  int n = wid >> 2, hh = wid & 3;
  float v = h[(size_t)n * D + hh * HID + lane];
  float s = v * asrc[hh * HID + lane];
  float d = v * adst[hh * HID + lane];
  #pragma unroll
  for (int off = 32; off; off >>= 1) {
    s += __shfl_down(s, off);
    d += __shfl_down(d, off);
  }
  if (lane == 0) { alps[wid] = s; alpd[wid] = d; }
}

// ================= CSR build (dst-grouped) =================
__global__ void count_k(const int* __restrict__ ei, int* __restrict__ deg) {
  int e = blockIdx.x * 256 + threadIdx.x;
  if (e >= E_TOT) return;
  int s, d; edge_sd(ei, e, s, d);
  atomicAdd(&deg[d], 1);
}

__global__ __launch_bounds__(SCAN_BS) void scan_block_k(const int* __restrict__ in,
                                                        int* __restrict__ out,
                                                        int* __restrict__ bsum, int n) {
  __shared__ int tmp[SCAN_BS];
  int g = blockIdx.x * SCAN_BS + threadIdx.x;
  tmp[threadIdx.x] = (g < n) ? in[g] : 0;
  __syncthreads();
  for (int off = 1; off < SCAN_BS; off <<= 1) {
    int t = 0;
    if ((int)threadIdx.x >= off) t = tmp[threadIdx.x - off];
    __syncthreads();
    if ((int)threadIdx.x >= off) tmp[threadIdx.x] += t;
    __syncthreads();
  }
  if (g < n) out[g] = tmp[threadIdx.x];
  if (threadIdx.x == SCAN_BS - 1) bsum[blockIdx.x] = tmp[SCAN_BS - 1];
}

__global__ void scan_top_k(int* __restrict__ bsum, int nb) {
  __shared__ int tmp[256];
  tmp[threadIdx.x] = ((int)threadIdx.x < nb) ? bsum[threadIdx.x] : 0;
  __syncthreads();
  for (int off = 1; off < 256; off <<= 1) {
    int t = 0;
    if ((int)threadIdx.x >= off) t = tmp[threadIdx.x - off];
    __syncthreads();
    if ((int)threadIdx.x >= off) tmp[threadIdx.x] += t;
    __syncthreads();
  }
  if ((int)threadIdx.x < nb) bsum[threadIdx.x] = tmp[threadIdx.x];
}

__global__ void add_off_k(const int* __restrict__ scan_out,
                          const int* __restrict__ bsum,
                          int* __restrict__ rowptr) {
  int g = blockIdx.x * 256 + threadIdx.x;
  if (g >= N_NODES) return;
  int blk = g / SCAN_BS;
  int add = blk ? bsum[blk - 1] : 0;
  rowptr[g + 1] = scan_out[g] + add;
  if (g == 0) rowptr[0] = 0;
}

__global__ void scatter_k(const int* __restrict__ ei,
                          const int* __restrict__ rowptr,
                          int* __restrict__ pos, int* __restrict__ csr) {
  int e = blockIdx.x * 256 + threadIdx.x;
  if (e >= E_TOT) return;
  int s, d; edge_sd(ei, e, s, d);
  int idx = rowptr[d] + atomicAdd(&pos[d], 1);
  csr[idx] = s;
}

// ====== fused segment-softmax + aggregation: one wave per node ======
// lane l owns channels 4l..4l+3 (head q = l>>4); h[src] read as coalesced float4
__global__ __launch_bounds__(256) void gat_gather_k(
    const int* __restrict__ rowptr, const int* __restrict__ csr,
    const float* __restrict__ alps, const float* __restrict__ alpd,
    const float* __restrict__ h, const float* __restrict__ b,
    float* __restrict__ out) {
  int wid = (blockIdx.x * 256 + threadIdx.x) >> 6;
  int lane = threadIdx.x & 63;
  if (wid >= N_NODES) return;
  int q = lane >> 4;                      // head of my 4 channels
  int beg = rowptr[wid], end = rowptr[wid + 1];
  float ad = alpd[wid * HEADS + q];

  // pass 1: per-head running max
  float m = -1e30f;
  for (int i = beg; i < end; ++i) {
    int s = csr[i];
    float x = alps[s * HEADS + q] + ad;
    float v = fmaxf(x, NEG_SLOPE * x);    // leaky_relu, slope<1
    m = fmaxf(m, v);
  }

  // pass 2: exp-weighted accumulate
  float den = 0.f;
  float4 acc = make_float4(0.f, 0.f, 0.f, 0.f);
  for (int i = beg; i < end; ++i) {
    int s = csr[i];
    float x = alps[s * HEADS + q] + ad;
    float v = fmaxf(x, NEG_SLOPE * x);
    float ef = __expf(v - m);
    den += ef;
    float4 hv = *(const float4*)(h + (size_t)s * D + lane * 4);
    acc.x += hv.x * ef; acc.y += hv.y * ef;
    acc.z += hv.z * ef; acc.w += hv.w * ef;
  }

  float inv = 1.f / (den + 1e-16f);
  float4 bv = *(const float4*)(b + lane * 4);
  float4 o;
  o.x = fmaxf(acc.x * inv + bv.x, 0.f);
  o.y = fmaxf(acc.y * inv + bv.y, 0.f);
  o.z = fmaxf(acc.z * inv + bv.z, 0.f);
  o.w = fmaxf(acc.w * inv + bv.w, 0.f);
  *(float4*)(out + (size_t)wid * D + lane * 4) = o;
}

// ---- pair scoring: one wave per pair ----
__global__ __launch_bounds__(256) void pair_k(const float* __restrict__ h,
                                              const int* __restrict__ pairs,
                                              const float* __restrict__ hw,
                                              const float* __restrict__ hb,
                                              float* __restrict__ out) {
  int wid = (blockIdx.x * 256 + threadIdx.x) >> 6;
  int lane = threadIdx.x & 63;
  if (wid >= P_PAIRS) return;
  int a = pairs[wid * 2], b = pairs[wid * 2 + 1];
  int half = lane >> 5;
  int l = lane & 31;
  const float* hp = h + (size_t)(half ? b : a) * D + l * 8;
  const float* wp = hw + half * D + l * 8;
  float4 v0 = *(const float4*)hp, v1 = *(const float4*)(hp + 4);
  float4 w0 = *(const float4*)wp, w1 = *(const float4*)(wp + 4);
  float s = v0.x * w0.x + v0.y * w0.y + v0.z * w0.z + v0.w * w0.w
          + v1.x * w1.x + v1.y * w1.y + v1.z * w1.z + v1.w * w1.w;
  #pragma unroll
  for (int off = 32; off; off >>= 1) s += __shfl_down(s, off);
  if (lane == 0) out[wid] = s + hb[0];
}

extern "C" void kernel_launch(void* const* d_in, const int* in_sizes, int n_in,
                              void* d_out, int out_size, void* d_ws, size_t ws_size,
                              hipStream_t stream) {
  const float* x    = (const float*)d_in[0];
  const int*   ei   = (const int*)d_in[1];
  const int*   prs  = (const int*)d_in[2];
  const float* W1   = (const float*)d_in[3];
  const float* as1  = (const float*)d_in[4];
  const float* ad1  = (const float*)d_in[5];
  const float* b1   = (const float*)d_in[6];
  const float* W2   = (const float*)d_in[7];
  const float* as2  = (const float*)d_in[8];
  const float* ad2  = (const float*)d_in[9];
  const float* b2   = (const float*)d_in[10];
  const float* hw   = (const float*)d_in[11];
  const float* hb   = (const float*)d_in[12];
  float* out = (float*)d_out;

  char* w = (char*)d_ws;
  float* buf0 = (float*)w;            w += (size_t)N_NODES * D * 4;   // h (GEMM out)
  float* buf1 = (float*)w;            w += (size_t)N_NODES * D * 4;   // layer out
  float* alps = (float*)w;            w += (size_t)N_NODES * HEADS * 4;
  float* alpd = (float*)w;            w += (size_t)N_NODES * HEADS * 4;
  int* rowptr = (int*)w;              w += (size_t)(N_NODES + 1) * 4;
  int* csr    = (int*)w;              w += (size_t)E_TOT * 4;

  // CSR-build temporaries aliased into buf1 (buf1 first written by gat_gather_k,
  // which runs strictly after scatter_k on this stream)
  int* deg      = (int*)buf1;
  int* scan_out = deg + N_NODES;
  int* bsum     = scan_out + N_NODES;   // up to 64 ints

  const int waveBlkNH = (N_NODES * HEADS) / 4;            // 50000
  const int eBlk     = (E_TOT + 255) / 256;               // 3321
  const int nScanBlk = (N_NODES + SCAN_BS - 1) / SCAN_BS; // 49
  const int nBlk256  = (N_NODES + 255) / 256;             // 196
  const int gatherBlk = (N_NODES * 64 + 255) / 256;       // 12500
  const int pairBlk  = (P_PAIRS + 3) / 4;                 // 50000
  const dim3 gemmGrid((N_NODES + 63) / 64, D / 64);       // 782 x 4

  // ---------- CSR build (once, reused by both layers) ----------
  hipMemsetAsync(deg, 0, (size_t)N_NODES * 4, stream);
  count_k<<<eBlk, 256, 0, stream>>>(ei, deg);
  scan_block_k<<<nScanBlk, SCAN_BS, 0, stream>>>(deg, scan_out, bsum, N_NODES);
  scan_top_k<<<1, 256, 0, stream>>>(bsum, nScanBlk);
  add_off_k<<<nBlk256, 256, 0, stream>>>(scan_out, bsum, rowptr);
  hipMemsetAsync(deg, 0, (size_t)N_NODES * 4, stream);   // reuse as pos
  scatter_k<<<eBlk, 256, 0, stream>>>(ei, rowptr, deg, csr);

  // ---------- layer 1 ----------
  gemm_tile<IN_DIM><<<gemmGrid, 256, 0, stream>>>(x, W1, buf0);
  alphas_k<<<waveBlkNH, 256, 0, stream>>>(buf0, as1, ad1, alps, alpd);
  gat_gather_k<<<gatherBlk, 256, 0, stream>>>(rowptr, csr, alps, alpd, buf0, b1, buf1);

  // ---------- layer 2 ----------
  gemm_tile<D><<<gemmGrid, 256, 0, stream>>>(buf1, W2, buf0);
  alphas_k<<<waveBlkNH, 256, 0, stream>>>(buf0, as2, ad2, alps, alpd);
  gat_gather_k<<<gatherBlk, 256, 0, stream>>>(rowptr, csr, alps, alpd, buf0, b2, buf1);

  // ---------- pair head ----------
  pair_k<<<pairBlk, 256, 0, stream>>>(buf1, prs, hw, hb, out);
}

// Round 4
// 587.778 us; speedup vs baseline: 4.1490x; 1.1913x over previous
//
#include <hip/hip_runtime.h>

#define N_NODES 50000
#define E_EDGES 800000
#define E_TOT   (E_EDGES + N_NODES)   // edges + self loops
#define P_PAIRS 200000
#define IN_DIM  32
#define HID     64
#define HEADS   4
#define D       256
#define NEG_SLOPE 0.2f
#define SCAN_BS 1024

__device__ __forceinline__ void edge_sd(const int* __restrict__ ei, int e, int& s, int& d) {
  if (e < E_EDGES) { s = ei[e]; d = ei[E_EDGES + e]; }
  else             { s = d = e - E_EDGES; }
}

// ================= register-blocked fp32 GEMM: [N,KD] @ [KD,256] =================
// 64x64 tile per block, 256 threads, 4x4 micro-tile per thread.
// blockIdx.y == head (64 cols == HID), so the attention logits alpha_src/alpha_dst
// are fused into the epilogue: per-row dot over this head's 64 channels.
template<int KD>
__global__ __launch_bounds__(256) void gemm_tile(const float* __restrict__ A,
                                                 const float* __restrict__ W,
                                                 const float* __restrict__ asrc,
                                                 const float* __restrict__ adst,
                                                 float* __restrict__ out,
                                                 float* __restrict__ alps,
                                                 float* __restrict__ alpd) {
  __shared__ float As[32][68];
  __shared__ float Bs[32][64];
  const int row0 = blockIdx.x * 64;
  const int col0 = blockIdx.y * 64;   // == q * HID
  const int q  = blockIdx.y;
  const int t  = threadIdx.x;
  const int tx = t & 15, ty = t >> 4;
  float acc[4][4] = {{0.f}};

  for (int kc = 0; kc < KD; kc += 32) {
    #pragma unroll
    for (int i = 0; i < 2; ++i) {
      int idx = t + i * 256;           // 0..511
      int r = idx >> 3, k4 = idx & 7;
      int rr = row0 + r;
      float4 a = make_float4(0.f, 0.f, 0.f, 0.f);
      if (rr < N_NODES) a = *(const float4*)(A + (size_t)rr * KD + kc + k4 * 4);
      As[k4 * 4 + 0][r] = a.x;
      As[k4 * 4 + 1][r] = a.y;
      As[k4 * 4 + 2][r] = a.z;
      As[k4 * 4 + 3][r] = a.w;
    }
    #pragma unroll
    for (int i = 0; i < 2; ++i) {
      int idx = t + i * 256;
      int k = idx >> 4, c4 = idx & 15;
      *(float4*)&Bs[k][c4 * 4] =
          *(const float4*)(W + (size_t)(kc + k) * D + col0 + c4 * 4);
    }
    __syncthreads();
    #pragma unroll
    for (int k = 0; k < 32; ++k) {
      float4 av = *(const float4*)&As[k][ty * 4];
      float4 bv = *(const float4*)&Bs[k][tx * 4];
      acc[0][0] += av.x * bv.x; acc[0][1] += av.x * bv.y;
      acc[0][2] += av.x * bv.z; acc[0][3] += av.x * bv.w;
      acc[1][0] += av.y * bv.x; acc[1][1] += av.y * bv.y;
      acc[1][2] += av.y * bv.z; acc[1][3] += av.y * bv.w;
      acc[2][0] += av.z * bv.x; acc[2][1] += av.z * bv.y;
      acc[2][2] += av.z * bv.z; acc[2][3] += av.z * bv.w;
      acc[3][0] += av.w * bv.x; acc[3][1] += av.w * bv.y;
      acc[3][2] += av.w * bv.z; acc[3][3] += av.w * bv.w;
    }
    __syncthreads();
  }

  // store h tile
  #pragma unroll
  for (int i = 0; i < 4; ++i) {
    int rr = row0 + ty * 4 + i;
    if (rr < N_NODES) {
      *(float4*)(out + (size_t)rr * D + col0 + tx * 4) =
          make_float4(acc[i][0], acc[i][1], acc[i][2], acc[i][3]);
    }
  }

  // fused attention logits: per row, dot over this head's 64 channels
  float ws[4], wd[4];
  #pragma unroll
  for (int j = 0; j < 4; ++j) {
    ws[j] = asrc[q * HID + tx * 4 + j];
    wd[j] = adst[q * HID + tx * 4 + j];
  }
  #pragma unroll
  for (int i = 0; i < 4; ++i) {
    float ps = acc[i][0] * ws[0] + acc[i][1] * ws[1]
             + acc[i][2] * ws[2] + acc[i][3] * ws[3];
    float pd = acc[i][0] * wd[0] + acc[i][1] * wd[1]
             + acc[i][2] * wd[2] + acc[i][3] * wd[3];
    #pragma unroll
    for (int off = 1; off < 16; off <<= 1) {
      ps += __shfl_xor(ps, off);
      pd += __shfl_xor(pd, off);
    }
    int rr = row0 + ty * 4 + i;
    if (tx == 0 && rr < N_NODES) {
      alps[rr * HEADS + q] = ps;
      alpd[rr * HEADS + q] = pd;
    }
  }
}

// ================= CSR build (dst-grouped) =================
__global__ void count_k(const int* __restrict__ ei, int* __restrict__ deg) {
  int e = blockIdx.x * 256 + threadIdx.x;
  if (e >= E_TOT) return;
  int s, d; edge_sd(ei, e, s, d);
  atomicAdd(&deg[d], 1);
}

__global__ __launch_bounds__(SCAN_BS) void scan_block_k(const int* __restrict__ in,
                                                        int* __restrict__ out,
                                                        int* __restrict__ bsum, int n) {
  __shared__ int tmp[SCAN_BS];
  int g = blockIdx.x * SCAN_BS + threadIdx.x;
  tmp[threadIdx.x] = (g < n) ? in[g] : 0;
  __syncthreads();
  for (int off = 1; off < SCAN_BS; off <<= 1) {
    int t = 0;
    if ((int)threadIdx.x >= off) t = tmp[threadIdx.x - off];
    __syncthreads();
    if ((int)threadIdx.x >= off) tmp[threadIdx.x] += t;
    __syncthreads();
  }
  if (g < n) out[g] = tmp[threadIdx.x];
  if (threadIdx.x == SCAN_BS - 1) bsum[blockIdx.x] = tmp[SCAN_BS - 1];
}

__global__ void scan_top_k(int* __restrict__ bsum, int nb) {
  __shared__ int tmp[256];
  tmp[threadIdx.x] = ((int)threadIdx.x < nb) ? bsum[threadIdx.x] : 0;
  __syncthreads();
  for (int off = 1; off < 256; off <<= 1) {
    int t = 0;
    if ((int)threadIdx.x >= off) t = tmp[threadIdx.x - off];
    __syncthreads();
    if ((int)threadIdx.x >= off) tmp[threadIdx.x] += t;
    __syncthreads();
  }
  if ((int)threadIdx.x < nb) bsum[threadIdx.x] = tmp[threadIdx.x];
}

__global__ void add_off_k(const int* __restrict__ scan_out,
                          const int* __restrict__ bsum,
                          int* __restrict__ rowptr) {
  int g = blockIdx.x * 256 + threadIdx.x;
  if (g >= N_NODES) return;
  int blk = g / SCAN_BS;
  int add = blk ? bsum[blk - 1] : 0;
  rowptr[g + 1] = scan_out[g] + add;
  if (g == 0) rowptr[0] = 0;
}

__global__ void scatter_k(const int* __restrict__ ei,
                          const int* __restrict__ rowptr,
                          int* __restrict__ pos, int* __restrict__ csr) {
  int e = blockIdx.x * 256 + threadIdx.x;
  if (e >= E_TOT) return;
  int s, d; edge_sd(ei, e, s, d);
  int idx = rowptr[d] + atomicAdd(&pos[d], 1);
  csr[idx] = s;
}

// ====== fused online-softmax aggregation: one wave per node, 4-edge batches ======
// lane l owns channels 4l..4l+3 (head q = l>>4); h[src] read as coalesced float4.
__global__ __launch_bounds__(256) void gat_gather_k(
    const int* __restrict__ rowptr, const int* __restrict__ csr,
    const float* __restrict__ alps, const float* __restrict__ alpd,
    const float* __restrict__ h, const float* __restrict__ b,
    float* __restrict__ out) {
  int wid = (blockIdx.x * 256 + threadIdx.x) >> 6;
  int lane = threadIdx.x & 63;
  if (wid >= N_NODES) return;
  int q = lane >> 4;
  int beg = rowptr[wid], end = rowptr[wid + 1];
  float ad = alpd[wid * HEADS + q];

  float m = -1e30f, den = 0.f;
  float4 acc = make_float4(0.f, 0.f, 0.f, 0.f);

  int i = beg;
  for (; i + 4 <= end; i += 4) {
    // 4 independent index loads, then 4 independent logit loads, then 4
    // independent 16B h loads -> 4-deep memory pipeline per wave
    int s0 = csr[i], s1 = csr[i + 1], s2 = csr[i + 2], s3 = csr[i + 3];
    float x0 = alps[s0 * HEADS + q], x1 = alps[s1 * HEADS + q];
    float x2 = alps[s2 * HEADS + q], x3 = alps[s3 * HEADS + q];
    float4 h0 = *(const float4*)(h + (size_t)s0 * D + lane * 4);
    float4 h1 = *(const float4*)(h + (size_t)s1 * D + lane * 4);
    float4 h2 = *(const float4*)(h + (size_t)s2 * D + lane * 4);
    float4 h3 = *(const float4*)(h + (size_t)s3 * D + lane * 4);
    float v0 = x0 + ad; v0 = fmaxf(v0, NEG_SLOPE * v0);
    float v1 = x1 + ad; v1 = fmaxf(v1, NEG_SLOPE * v1);
    float v2 = x2 + ad; v2 = fmaxf(v2, NEG_SLOPE * v2);
    float v3 = x3 + ad; v3 = fmaxf(v3, NEG_SLOPE * v3);
    float mn = fmaxf(fmaxf(fmaxf(v0, v1), fmaxf(v2, v3)), m);
    float c  = __expf(m - mn);                 // 0 on first batch, 1 if no growth
    float e0 = __expf(v0 - mn), e1 = __expf(v1 - mn);
    float e2 = __expf(v2 - mn), e3 = __expf(v3 - mn);
    den = den * c + (e0 + e1) + (e2 + e3);
    acc.x = acc.x * c + e0 * h0.x + e1 * h1.x + e2 * h2.x + e3 * h3.x;
    acc.y = acc.y * c + e0 * h0.y + e1 * h1.y + e2 * h2.y + e3 * h3.y;
    acc.z = acc.z * c + e0 * h0.z + e1 * h1.z + e2 * h2.z + e3 * h3.z;
    acc.w = acc.w * c + e0 * h0.w + e1 * h1.w + e2 * h2.w + e3 * h3.w;
    m = mn;
  }
  for (; i < end; ++i) {
    int s = csr[i];
    float x = alps[s * HEADS + q] + ad;
    float v = fmaxf(x, NEG_SLOPE * x);
    float4 hv = *(const float4*)(h + (size_t)s * D + lane * 4);
    float mn = fmaxf(v, m);
    float c  = __expf(m - mn);
    float e  = __expf(v - mn);
    den = den * c + e;
    acc.x = acc.x * c + e * hv.x;
    acc.y = acc.y * c + e * hv.y;
    acc.z = acc.z * c + e * hv.z;
    acc.w = acc.w * c + e * hv.w;
    m = mn;
  }

  float inv = 1.f / (den + 1e-16f);
  float4 bv = *(const float4*)(b + lane * 4);
  float4 o;
  o.x = fmaxf(acc.x * inv + bv.x, 0.f);
  o.y = fmaxf(acc.y * inv + bv.y, 0.f);
  o.z = fmaxf(acc.z * inv + bv.z, 0.f);
  o.w = fmaxf(acc.w * inv + bv.w, 0.f);
  *(float4*)(out + (size_t)wid * D + lane * 4) = o;
}

// ---- head GEMV: u[n] = h[n]·hw[0:256], v[n] = h[n]·hw[256:512] ----
__global__ __launch_bounds__(256) void head_gemv_k(const float* __restrict__ h,
                                                   const float* __restrict__ hw,
                                                   float* __restrict__ u,
                                                   float* __restrict__ v) {
  int wid = (blockIdx.x * 256 + threadIdx.x) >> 6;
  int lane = threadIdx.x & 63;
  if (wid >= N_NODES) return;
  float4 hv = *(const float4*)(h + (size_t)wid * D + lane * 4);
  float4 w0 = *(const float4*)(hw + lane * 4);
  float4 w1 = *(const float4*)(hw + D + lane * 4);
  float su = hv.x * w0.x + hv.y * w0.y + hv.z * w0.z + hv.w * w0.w;
  float sv = hv.x * w1.x + hv.y * w1.y + hv.z * w1.z + hv.w * w1.w;
  #pragma unroll
  for (int off = 32; off; off >>= 1) {
    su += __shfl_down(su, off);
    sv += __shfl_down(sv, off);
  }
  if (lane == 0) { u[wid] = su; v[wid] = sv; }
}

// ---- pair lookup: out[p] = u[a] + v[b] + hb ----
__global__ void pair_lu_k(const int* __restrict__ pairs,
                          const float* __restrict__ u, const float* __restrict__ v,
                          const float* __restrict__ hb, float* __restrict__ out) {
  int g = blockIdx.x * 256 + threadIdx.x;
  if (g >= P_PAIRS) return;
  int a = pairs[g * 2], b = pairs[g * 2 + 1];
  out[g] = u[a] + v[b] + hb[0];
}

extern "C" void kernel_launch(void* const* d_in, const int* in_sizes, int n_in,
                              void* d_out, int out_size, void* d_ws, size_t ws_size,
                              hipStream_t stream) {
  const float* x    = (const float*)d_in[0];
  const int*   ei   = (const int*)d_in[1];
  const int*   prs  = (const int*)d_in[2];
  const float* W1   = (const float*)d_in[3];
  const float* as1  = (const float*)d_in[4];
  const float* ad1  = (const float*)d_in[5];
  const float* b1   = (const float*)d_in[6];
  const float* W2   = (const float*)d_in[7];
  const float* as2  = (const float*)d_in[8];
  const float* ad2  = (const float*)d_in[9];
  const float* b2   = (const float*)d_in[10];
  const float* hw   = (const float*)d_in[11];
  const float* hb   = (const float*)d_in[12];
  float* out = (float*)d_out;

  char* w = (char*)d_ws;
  float* buf0 = (float*)w;            w += (size_t)N_NODES * D * 4;   // h (GEMM out)
  float* buf1 = (float*)w;            w += (size_t)N_NODES * D * 4;   // layer out
  float* alps = (float*)w;            w += (size_t)N_NODES * HEADS * 4;
  float* alpd = (float*)w;            w += (size_t)N_NODES * HEADS * 4;
  int* rowptr = (int*)w;              w += (size_t)(N_NODES + 1) * 4;
  int* csr    = (int*)w;              w += (size_t)E_TOT * 4;
  float* uu   = (float*)w;            w += (size_t)N_NODES * 4;
  float* vv   = (float*)w;            w += (size_t)N_NODES * 4;

  // CSR-build temporaries aliased into buf1 (buf1 first written by gat_gather_k,
  // which runs strictly after scatter_k on this stream)
  int* deg      = (int*)buf1;
  int* scan_out = deg + N_NODES;
  int* bsum     = scan_out + N_NODES;   // up to 64 ints

  const int eBlk     = (E_TOT + 255) / 256;               // 3321
  const int nScanBlk = (N_NODES + SCAN_BS - 1) / SCAN_BS; // 49
  const int nBlk256  = (N_NODES + 255) / 256;             // 196
  const int waveBlk  = (N_NODES * 64 + 255) / 256;        // 12500
  const int pairBlk  = (P_PAIRS + 255) / 256;             // 782
  const dim3 gemmGrid((N_NODES + 63) / 64, D / 64);       // 782 x 4

  // ---------- CSR build (once, reused by both layers) ----------
  hipMemsetAsync(deg, 0, (size_t)N_NODES * 4, stream);
  count_k<<<eBlk, 256, 0, stream>>>(ei, deg);
  scan_block_k<<<nScanBlk, SCAN_BS, 0, stream>>>(deg, scan_out, bsum, N_NODES);
  scan_top_k<<<1, 256, 0, stream>>>(bsum, nScanBlk);
  add_off_k<<<nBlk256, 256, 0, stream>>>(scan_out, bsum, rowptr);
  hipMemsetAsync(deg, 0, (size_t)N_NODES * 4, stream);   // reuse as pos
  scatter_k<<<eBlk, 256, 0, stream>>>(ei, rowptr, deg, csr);

  // ---------- layer 1 ----------
  gemm_tile<IN_DIM><<<gemmGrid, 256, 0, stream>>>(x, W1, as1, ad1, buf0, alps, alpd);
  gat_gather_k<<<waveBlk, 256, 0, stream>>>(rowptr, csr, alps, alpd, buf0, b1, buf1);

  // ---------- layer 2 ----------
  gemm_tile<D><<<gemmGrid, 256, 0, stream>>>(buf1, W2, as2, ad2, buf0, alps, alpd);
  gat_gather_k<<<waveBlk, 256, 0, stream>>>(rowptr, csr, alps, alpd, buf0, b2, buf1);

  // ---------- pair head ----------
  head_gemv_k<<<waveBlk, 256, 0, stream>>>(buf1, hw, uu, vv);
  pair_lu_k<<<pairBlk, 256, 0, stream>>>(prs, uu, vv, hb, out);
}

// Round 5
// 510.528 us; speedup vs baseline: 4.7768x; 1.1513x over previous
//
#include <hip/hip_runtime.h>

#define N_NODES 50000
#define E_EDGES 800000
#define E_TOT   (E_EDGES + N_NODES)   // edges + self loops
#define P_PAIRS 200000
#define IN_DIM  32
#define HID     64
#define HEADS   4
#define D       256
#define NEG_SLOPE 0.2f
#define SCAN_BS 1024
#define LOG2E 1.4426950408889634f

__device__ __forceinline__ float ex2(float v) { return __builtin_amdgcn_exp2f(v); }

__device__ __forceinline__ void edge_sd(const int* __restrict__ ei, int e, int& s, int& d) {
  if (e < E_EDGES) { s = ei[e]; d = ei[E_EDGES + e]; }
  else             { s = d = e - E_EDGES; }
}

// ================= CSR build (dst-grouped) =================
__global__ void count_k(const int* __restrict__ ei, int* __restrict__ deg) {
  int e = blockIdx.x * 256 + threadIdx.x;
  if (e >= E_TOT) return;
  int s, d; edge_sd(ei, e, s, d);
  atomicAdd(&deg[d], 1);
}

__global__ __launch_bounds__(SCAN_BS) void scan_block_k(const int* __restrict__ in,
                                                        int* __restrict__ out,
                                                        int* __restrict__ bsum, int n) {
  __shared__ int tmp[SCAN_BS];
  int g = blockIdx.x * SCAN_BS + threadIdx.x;
  tmp[threadIdx.x] = (g < n) ? in[g] : 0;
  __syncthreads();
  for (int off = 1; off < SCAN_BS; off <<= 1) {
    int t = 0;
    if ((int)threadIdx.x >= off) t = tmp[threadIdx.x - off];
    __syncthreads();
    if ((int)threadIdx.x >= off) tmp[threadIdx.x] += t;
    __syncthreads();
  }
  if (g < n) out[g] = tmp[threadIdx.x];
  if (threadIdx.x == SCAN_BS - 1) bsum[blockIdx.x] = tmp[SCAN_BS - 1];
}

__global__ void scan_top_k(int* __restrict__ bsum, int nb) {
  __shared__ int tmp[256];
  tmp[threadIdx.x] = ((int)threadIdx.x < nb) ? bsum[threadIdx.x] : 0;
  __syncthreads();
  for (int off = 1; off < 256; off <<= 1) {
    int t = 0;
    if ((int)threadIdx.x >= off) t = tmp[threadIdx.x - off];
    __syncthreads();
    if ((int)threadIdx.x >= off) tmp[threadIdx.x] += t;
    __syncthreads();
  }
  if ((int)threadIdx.x < nb) bsum[threadIdx.x] = tmp[threadIdx.x];
}

__global__ void add_off_k(const int* __restrict__ scan_out,
                          const int* __restrict__ bsum,
                          int* __restrict__ rowptr) {
  int g = blockIdx.x * 256 + threadIdx.x;
  if (g >= N_NODES) return;
  int blk = g / SCAN_BS;
  int add = blk ? bsum[blk - 1] : 0;
  rowptr[g + 1] = scan_out[g] + add;
  if (g == 0) rowptr[0] = 0;
}

__global__ void scatter_k(const int* __restrict__ ei,
                          const int* __restrict__ rowptr,
                          int* __restrict__ pos, int* __restrict__ csr) {
  int e = blockIdx.x * 256 + threadIdx.x;
  if (e >= E_TOT) return;
  int s, d; edge_sd(ei, e, s, d);
  int idx = rowptr[d] + atomicAdd(&pos[d], 1);
  csr[idx] = s;
}

// ================ layer-1 algebraic restructure ================
// Wa1[k][h] = sum_c W1[k, h*64+c] * att[h,c]  (pre-scaled by LOG2E)
__global__ void prep_wa1_k(const float* __restrict__ W1,
                           const float* __restrict__ as1,
                           const float* __restrict__ ad1,
                           float* __restrict__ wa_s, float* __restrict__ wa_d) {
  int t = threadIdx.x;                  // one block of 256
  int kk = (t >> 2) & 31, h = t & 3;
  const float* att = (t < 128) ? as1 : ad1;
  float sum = 0.f;
  for (int c = 0; c < HID; ++c) sum += W1[kk * D + h * HID + c] * att[h * HID + c];
  float* dst = (t < 128) ? wa_s : wa_d;
  dst[kk * 4 + h] = sum * LOG2E;
}

// alps1[n,h] = x[n] . wa_s[:,h] ; 8 lanes per node, 8 nodes per wave
__global__ __launch_bounds__(256) void alphas1_k(const float* __restrict__ x,
                                                 const float* __restrict__ wa_s,
                                                 const float* __restrict__ wa_d,
                                                 float* __restrict__ alps,
                                                 float* __restrict__ alpd) {
  int w = (blockIdx.x * 256 + threadIdx.x) >> 6;
  int lane = threadIdx.x & 63;
  int n = w * 8 + (lane >> 3);
  int j = lane & 7;
  float4 xv = make_float4(0.f, 0.f, 0.f, 0.f);
  if (n < N_NODES) xv = *(const float4*)(x + (size_t)n * IN_DIM + j * 4);
  float ps[4] = {0.f, 0.f, 0.f, 0.f}, pd[4] = {0.f, 0.f, 0.f, 0.f};
  #pragma unroll
  for (int kk = 0; kk < 4; ++kk) {
    float xk = ((const float*)&xv)[kk];
    float4 ws = *(const float4*)(wa_s + (j * 4 + kk) * 4);
    float4 wd = *(const float4*)(wa_d + (j * 4 + kk) * 4);
    ps[0] += xk * ws.x; ps[1] += xk * ws.y; ps[2] += xk * ws.z; ps[3] += xk * ws.w;
    pd[0] += xk * wd.x; pd[1] += xk * wd.y; pd[2] += xk * wd.z; pd[3] += xk * wd.w;
  }
  #pragma unroll
  for (int off = 1; off < 8; off <<= 1) {
    #pragma unroll
    for (int h = 0; h < 4; ++h) {
      ps[h] += __shfl_xor(ps[h], off);
      pd[h] += __shfl_xor(pd[h], off);
    }
  }
  if (j == 0 && n < N_NODES) {
    *(float4*)(alps + n * 4) = make_float4(ps[0], ps[1], ps[2], ps[3]);
    *(float4*)(alpd + n * 4) = make_float4(pd[0], pd[1], pd[2], pd[3]);
  }
}

// x-space gather: agg[n][h][k<32] = (sum_e exp2 w * x[src][k]) / den[h]
// half-wave (32 lanes) per node, lane = channel; all 4 heads in registers.
__global__ __launch_bounds__(256) void gat_gather1_k(
    const int* __restrict__ rowptr, const int* __restrict__ csr,
    const float* __restrict__ alps, const float* __restrict__ alpd,
    const float* __restrict__ x, float* __restrict__ agg) {
  int wid2 = (blockIdx.x * 256 + threadIdx.x) >> 6;
  int lane = threadIdx.x & 63;
  int half = lane >> 5, l = lane & 31;
  int n = wid2 * 2 + half;
  bool valid = n < N_NODES;
  int beg = valid ? rowptr[n] : 0;
  int end = valid ? rowptr[n + 1] : 0;
  float4 ad4 = make_float4(0.f, 0.f, 0.f, 0.f);
  if (valid) ad4 = *(const float4*)(alpd + n * 4);
  float m[4], den[4], acc[4];
  #pragma unroll
  for (int h = 0; h < 4; ++h) { m[h] = -1e30f; den[h] = 0.f; acc[h] = 0.f; }

  for (int i = beg; i < end; i += 4) {
    int s[4]; bool ok[4]; float4 al[4]; float xv[4];
    #pragma unroll
    for (int j = 0; j < 4; ++j) { ok[j] = (i + j) < end; s[j] = ok[j] ? csr[i + j] : 0; }
    #pragma unroll
    for (int j = 0; j < 4; ++j) al[j] = *(const float4*)(alps + s[j] * 4);
    #pragma unroll
    for (int j = 0; j < 4; ++j) xv[j] = x[(size_t)s[j] * IN_DIM + l];
    #pragma unroll
    for (int h = 0; h < 4; ++h) {
      float v[4];
      #pragma unroll
      for (int j = 0; j < 4; ++j) {
        float t = ((const float*)&al[j])[h] + ((const float*)&ad4)[h];
        t = fmaxf(t, NEG_SLOPE * t);
        v[j] = ok[j] ? t : -1e30f;
      }
      float mn = fmaxf(fmaxf(fmaxf(v[0], v[1]), fmaxf(v[2], v[3])), m[h]);
      float c  = ex2(m[h] - mn);
      float e0 = ex2(v[0] - mn), e1 = ex2(v[1] - mn);
      float e2 = ex2(v[2] - mn), e3 = ex2(v[3] - mn);
      den[h] = den[h] * c + (e0 + e1) + (e2 + e3);
      acc[h] = acc[h] * c + e0 * xv[0] + e1 * xv[1] + e2 * xv[2] + e3 * xv[3];
      m[h] = mn;
    }
  }
  if (valid) {
    #pragma unroll
    for (int h = 0; h < 4; ++h)
      agg[(size_t)n * 128 + h * 32 + l] = acc[h] / (den[h] + 1e-16f);
  }
}

// out1[n, q*64+c] = relu(agg[n,q,:] @ W1[:, q*64+c] + b1)
__global__ __launch_bounds__(256) void gemm_head1(const float* __restrict__ agg,
                                                  const float* __restrict__ W,
                                                  const float* __restrict__ b,
                                                  float* __restrict__ out) {
  __shared__ float As[32][68];
  __shared__ float Bs[32][64];
  const int row0 = blockIdx.x * 64;
  const int q = blockIdx.y;
  const int col0 = q * 64;
  const int t = threadIdx.x, tx = t & 15, ty = t >> 4;
  #pragma unroll
  for (int i = 0; i < 2; ++i) {
    int idx = t + i * 256;
    int r = idx >> 3, k4 = idx & 7;
    int rr = row0 + r;
    float4 a = make_float4(0.f, 0.f, 0.f, 0.f);
    if (rr < N_NODES) a = *(const float4*)(agg + (size_t)rr * 128 + q * 32 + k4 * 4);
    As[k4 * 4 + 0][r] = a.x;
    As[k4 * 4 + 1][r] = a.y;
    As[k4 * 4 + 2][r] = a.z;
    As[k4 * 4 + 3][r] = a.w;
  }
  #pragma unroll
  for (int i = 0; i < 2; ++i) {
    int idx = t + i * 256;
    int k = idx >> 4, c4 = idx & 15;
    *(float4*)&Bs[k][c4 * 4] = *(const float4*)(W + (size_t)k * D + col0 + c4 * 4);
  }
  __syncthreads();
  float acc[4][4] = {{0.f}};
  #pragma unroll
  for (int k = 0; k < 32; ++k) {
    float4 av = *(const float4*)&As[k][ty * 4];
    float4 bv = *(const float4*)&Bs[k][tx * 4];
    acc[0][0] += av.x * bv.x; acc[0][1] += av.x * bv.y;
    acc[0][2] += av.x * bv.z; acc[0][3] += av.x * bv.w;
    acc[1][0] += av.y * bv.x; acc[1][1] += av.y * bv.y;
    acc[1][2] += av.y * bv.z; acc[1][3] += av.y * bv.w;
    acc[2][0] += av.z * bv.x; acc[2][1] += av.z * bv.y;
    acc[2][2] += av.z * bv.z; acc[2][3] += av.z * bv.w;
    acc[3][0] += av.w * bv.x; acc[3][1] += av.w * bv.y;
    acc[3][2] += av.w * bv.z; acc[3][3] += av.w * bv.w;
  }
  float4 bv = *(const float4*)(b + col0 + tx * 4);
  #pragma unroll
  for (int i = 0; i < 4; ++i) {
    int rr = row0 + ty * 4 + i;
    if (rr < N_NODES) {
      float4 o;
      o.x = fmaxf(acc[i][0] + bv.x, 0.f);
      o.y = fmaxf(acc[i][1] + bv.y, 0.f);
      o.z = fmaxf(acc[i][2] + bv.z, 0.f);
      o.w = fmaxf(acc[i][3] + bv.w, 0.f);
      *(float4*)(out + (size_t)rr * D + col0 + tx * 4) = o;
    }
  }
}

// ============== layer-2 GEMM with fused logits (pre-scaled by LOG2E) ==============
template<int KD>
__global__ __launch_bounds__(256) void gemm_tile(const float* __restrict__ A,
                                                 const float* __restrict__ W,
                                                 const float* __restrict__ asrc,
                                                 const float* __restrict__ adst,
                                                 float* __restrict__ out,
                                                 float* __restrict__ alps,
                                                 float* __restrict__ alpd) {
  __shared__ float As[32][68];
  __shared__ float Bs[32][64];
  const int row0 = blockIdx.x * 64;
  const int col0 = blockIdx.y * 64;   // == q * HID
  const int q  = blockIdx.y;
  const int t  = threadIdx.x;
  const int tx = t & 15, ty = t >> 4;
  float acc[4][4] = {{0.f}};

  for (int kc = 0; kc < KD; kc += 32) {
    #pragma unroll
    for (int i = 0; i < 2; ++i) {
      int idx = t + i * 256;
      int r = idx >> 3, k4 = idx & 7;
      int rr = row0 + r;
      float4 a = make_float4(0.f, 0.f, 0.f, 0.f);
      if (rr < N_NODES) a = *(const float4*)(A + (size_t)rr * KD + kc + k4 * 4);
      As[k4 * 4 + 0][r] = a.x;
      As[k4 * 4 + 1][r] = a.y;
      As[k4 * 4 + 2][r] = a.z;
      As[k4 * 4 + 3][r] = a.w;
    }
    #pragma unroll
    for (int i = 0; i < 2; ++i) {
      int idx = t + i * 256;
      int k = idx >> 4, c4 = idx & 15;
      *(float4*)&Bs[k][c4 * 4] =
          *(const float4*)(W + (size_t)(kc + k) * D + col0 + c4 * 4);
    }
    __syncthreads();
    #pragma unroll
    for (int k = 0; k < 32; ++k) {
      float4 av = *(const float4*)&As[k][ty * 4];
      float4 bv = *(const float4*)&Bs[k][tx * 4];
      acc[0][0] += av.x * bv.x; acc[0][1] += av.x * bv.y;
      acc[0][2] += av.x * bv.z; acc[0][3] += av.x * bv.w;
      acc[1][0] += av.y * bv.x; acc[1][1] += av.y * bv.y;
      acc[1][2] += av.y * bv.z; acc[1][3] += av.y * bv.w;
      acc[2][0] += av.z * bv.x; acc[2][1] += av.z * bv.y;
      acc[2][2] += av.z * bv.z; acc[2][3] += av.z * bv.w;
      acc[3][0] += av.w * bv.x; acc[3][1] += av.w * bv.y;
      acc[3][2] += av.w * bv.z; acc[3][3] += av.w * bv.w;
    }
    __syncthreads();
  }

  #pragma unroll
  for (int i = 0; i < 4; ++i) {
    int rr = row0 + ty * 4 + i;
    if (rr < N_NODES) {
      *(float4*)(out + (size_t)rr * D + col0 + tx * 4) =
          make_float4(acc[i][0], acc[i][1], acc[i][2], acc[i][3]);
    }
  }

  float ws[4], wd[4];
  #pragma unroll
  for (int j = 0; j < 4; ++j) {
    ws[j] = asrc[q * HID + tx * 4 + j];
    wd[j] = adst[q * HID + tx * 4 + j];
  }
  #pragma unroll
  for (int i = 0; i < 4; ++i) {
    float ps = acc[i][0] * ws[0] + acc[i][1] * ws[1]
             + acc[i][2] * ws[2] + acc[i][3] * ws[3];
    float pd = acc[i][0] * wd[0] + acc[i][1] * wd[1]
             + acc[i][2] * wd[2] + acc[i][3] * wd[3];
    #pragma unroll
    for (int off = 1; off < 16; off <<= 1) {
      ps += __shfl_xor(ps, off);
      pd += __shfl_xor(pd, off);
    }
    int rr = row0 + ty * 4 + i;
    if (tx == 0 && rr < N_NODES) {
      alps[rr * HEADS + q] = ps * LOG2E;
      alpd[rr * HEADS + q] = pd * LOG2E;
    }
  }
}

// ====== 256-wide online-softmax gather: one wave per node, 6-edge batches ======
__global__ __launch_bounds__(256) void gat_gather_k(
    const int* __restrict__ rowptr, const int* __restrict__ csr,
    const float* __restrict__ alps, const float* __restrict__ alpd,
    const float* __restrict__ h, const float* __restrict__ b,
    float* __restrict__ out) {
  int wid = (blockIdx.x * 256 + threadIdx.x) >> 6;
  int lane = threadIdx.x & 63;
  if (wid >= N_NODES) return;
  int q = lane >> 4;
  int beg = rowptr[wid], end = rowptr[wid + 1];
  float ad = alpd[wid * HEADS + q];

  float m = -1e30f, den = 0.f;
  float4 acc = make_float4(0.f, 0.f, 0.f, 0.f);

  for (int i = beg; i < end; i += 6) {
    int s[6]; bool ok[6]; float xl[6]; float4 hv[6];
    #pragma unroll
    for (int j = 0; j < 6; ++j) { ok[j] = (i + j) < end; s[j] = ok[j] ? csr[i + j] : 0; }
    #pragma unroll
    for (int j = 0; j < 6; ++j) xl[j] = alps[s[j] * HEADS + q];
    #pragma unroll
    for (int j = 0; j < 6; ++j) hv[j] = *(const float4*)(h + (size_t)s[j] * D + lane * 4);
    float v[6];
    #pragma unroll
    for (int j = 0; j < 6; ++j) {
      float t = xl[j] + ad;
      t = fmaxf(t, NEG_SLOPE * t);
      v[j] = ok[j] ? t : -1e30f;
    }
    float mn = fmaxf(m, fmaxf(fmaxf(fmaxf(v[0], v[1]), fmaxf(v[2], v[3])),
                              fmaxf(v[4], v[5])));
    float c = ex2(m - mn);
    float e[6];
    #pragma unroll
    for (int j = 0; j < 6; ++j) e[j] = ex2(v[j] - mn);
    den = den * c + ((e[0] + e[1]) + (e[2] + e[3])) + (e[4] + e[5]);
    acc.x = acc.x * c + e[0]*hv[0].x + e[1]*hv[1].x + e[2]*hv[2].x + e[3]*hv[3].x + e[4]*hv[4].x + e[5]*hv[5].x;
    acc.y = acc.y * c + e[0]*hv[0].y + e[1]*hv[1].y + e[2]*hv[2].y + e[3]*hv[3].y + e[4]*hv[4].y + e[5]*hv[5].y;
    acc.z = acc.z * c + e[0]*hv[0].z + e[1]*hv[1].z + e[2]*hv[2].z + e[3]*hv[3].z + e[4]*hv[4].z + e[5]*hv[5].z;
    acc.w = acc.w * c + e[0]*hv[0].w + e[1]*hv[1].w + e[2]*hv[2].w + e[3]*hv[3].w + e[4]*hv[4].w + e[5]*hv[5].w;
    m = mn;
  }

  float inv = 1.f / (den + 1e-16f);
  float4 bv = *(const float4*)(b + lane * 4);
  float4 o;
  o.x = fmaxf(acc.x * inv + bv.x, 0.f);
  o.y = fmaxf(acc.y * inv + bv.y, 0.f);
  o.z = fmaxf(acc.z * inv + bv.z, 0.f);
  o.w = fmaxf(acc.w * inv + bv.w, 0.f);
  *(float4*)(out + (size_t)wid * D + lane * 4) = o;
}

// ---- head GEMV: u[n] = h[n]·hw[0:256], v[n] = h[n]·hw[256:512] ----
__global__ __launch_bounds__(256) void head_gemv_k(const float* __restrict__ h,
                                                   const float* __restrict__ hw,
                                                   float* __restrict__ u,
                                                   float* __restrict__ v) {
  int wid = (blockIdx.x * 256 + threadIdx.x) >> 6;
  int lane = threadIdx.x & 63;
  if (wid >= N_NODES) return;
  float4 hv = *(const float4*)(h + (size_t)wid * D + lane * 4);
  float4 w0 = *(const float4*)(hw + lane * 4);
  float4 w1 = *(const float4*)(hw + D + lane * 4);
  float su = hv.x * w0.x + hv.y * w0.y + hv.z * w0.z + hv.w * w0.w;
  float sv = hv.x * w1.x + hv.y * w1.y + hv.z * w1.z + hv.w * w1.w;
  #pragma unroll
  for (int off = 32; off; off >>= 1) {
    su += __shfl_down(su, off);
    sv += __shfl_down(sv, off);
  }
  if (lane == 0) { u[wid] = su; v[wid] = sv; }
}

// ---- pair lookup: out[p] = u[a] + v[b] + hb ----
__global__ void pair_lu_k(const int* __restrict__ pairs,
                          const float* __restrict__ u, const float* __restrict__ v,
                          const float* __restrict__ hb, float* __restrict__ out) {
  int g = blockIdx.x * 256 + threadIdx.x;
  if (g >= P_PAIRS) return;
  int a = pairs[g * 2], b = pairs[g * 2 + 1];
  out[g] = u[a] + v[b] + hb[0];
}

extern "C" void kernel_launch(void* const* d_in, const int* in_sizes, int n_in,
                              void* d_out, int out_size, void* d_ws, size_t ws_size,
                              hipStream_t stream) {
  const float* x    = (const float*)d_in[0];
  const int*   ei   = (const int*)d_in[1];
  const int*   prs  = (const int*)d_in[2];
  const float* W1   = (const float*)d_in[3];
  const float* as1  = (const float*)d_in[4];
  const float* ad1  = (const float*)d_in[5];
  const float* b1   = (const float*)d_in[6];
  const float* W2   = (const float*)d_in[7];
  const float* as2  = (const float*)d_in[8];
  const float* ad2  = (const float*)d_in[9];
  const float* b2   = (const float*)d_in[10];
  const float* hw   = (const float*)d_in[11];
  const float* hb   = (const float*)d_in[12];
  float* out = (float*)d_out;

  char* w = (char*)d_ws;
  float* buf0 = (float*)w;            w += (size_t)N_NODES * D * 4;   // agg1 / h2
  float* buf1 = (float*)w;            w += (size_t)N_NODES * D * 4;   // out1 / out2
  float* alps = (float*)w;            w += (size_t)N_NODES * HEADS * 4;
  float* alpd = (float*)w;            w += (size_t)N_NODES * HEADS * 4;
  int* rowptr = (int*)w;              w += (size_t)(N_NODES + 1) * 4;
  int* csr    = (int*)w;              w += (size_t)E_TOT * 4;
  float* uu   = (float*)w;            w += (size_t)N_NODES * 4;
  float* vv   = (float*)w;            w += (size_t)N_NODES * 4;
  float* wa_s = (float*)w;            w += 128 * 4;
  float* wa_d = (float*)w;            w += 128 * 4;

  // CSR-build temporaries aliased into buf1 (first real write to buf1 is
  // gemm_head1, which runs strictly after scatter_k on this stream)
  int* deg      = (int*)buf1;
  int* scan_out = deg + N_NODES;
  int* bsum     = scan_out + N_NODES;

  const int eBlk     = (E_TOT + 255) / 256;               // 3321
  const int nScanBlk = (N_NODES + SCAN_BS - 1) / SCAN_BS; // 49
  const int nBlk256  = (N_NODES + 255) / 256;             // 196
  const int waveBlk  = (N_NODES * 64 + 255) / 256;        // 12500
  const int a1Blk    = (N_NODES * 8 + 255) / 256;         // 1563
  const int g1Blk    = ((N_NODES + 1) / 2 * 64 + 255) / 256; // 6250
  const int pairBlk  = (P_PAIRS + 255) / 256;             // 782
  const dim3 gemmGrid((N_NODES + 63) / 64, D / 64);       // 782 x 4

  // ---------- CSR build (once, reused by both layers) ----------
  hipMemsetAsync(deg, 0, (size_t)N_NODES * 4, stream);
  count_k<<<eBlk, 256, 0, stream>>>(ei, deg);
  scan_block_k<<<nScanBlk, SCAN_BS, 0, stream>>>(deg, scan_out, bsum, N_NODES);
  scan_top_k<<<1, 256, 0, stream>>>(bsum, nScanBlk);
  add_off_k<<<nBlk256, 256, 0, stream>>>(scan_out, bsum, rowptr);
  hipMemsetAsync(deg, 0, (size_t)N_NODES * 4, stream);   // reuse as pos
  scatter_k<<<eBlk, 256, 0, stream>>>(ei, rowptr, deg, csr);

  // ---------- layer 1 (x-space aggregation) ----------
  prep_wa1_k<<<1, 256, 0, stream>>>(W1, as1, ad1, wa_s, wa_d);
  alphas1_k<<<a1Blk, 256, 0, stream>>>(x, wa_s, wa_d, alps, alpd);
  gat_gather1_k<<<g1Blk, 256, 0, stream>>>(rowptr, csr, alps, alpd, x, buf0);
  gemm_head1<<<gemmGrid, 256, 0, stream>>>(buf0, W1, b1, buf1);

  // ---------- layer 2 ----------
  gemm_tile<D><<<gemmGrid, 256, 0, stream>>>(buf1, W2, as2, ad2, buf0, alps, alpd);
  gat_gather_k<<<waveBlk, 256, 0, stream>>>(rowptr, csr, alps, alpd, buf0, b2, buf1);

  // ---------- pair head ----------
  head_gemv_k<<<waveBlk, 256, 0, stream>>>(buf1, hw, uu, vv);
  pair_lu_k<<<pairBlk, 256, 0, stream>>>(prs, uu, vv, hb, out);
}